// Round 12
// baseline (220.809 us; speedup 1.0000x reference)
//
#include <hip/hip_runtime.h>

typedef float f32x4 __attribute__((ext_vector_type(4)));
typedef float f32x16 __attribute__((ext_vector_type(16)));
typedef short bf16x8 __attribute__((ext_vector_type(8)));
typedef unsigned short u16;
typedef unsigned int u32;

#define MFMA(a, b, c) __builtin_amdgcn_mfma_f32_16x16x32_bf16((a), (b), (c), 0, 0, 0)
#define MFMA32(a, b, c) __builtin_amdgcn_mfma_f32_32x32x16_bf16((a), (b), (c), 0, 0, 0)

static __device__ __forceinline__ u16 f2bf(float f) {
    union { float f; u32 u; } v; v.f = f;
    u32 r = v.u + 0x7FFFu + ((v.u >> 16) & 1u);
    return (u16)(r >> 16);
}

// pack two fp32 -> two bf16 in one u32 (a low, b high)
static __device__ __forceinline__ u32 pkbf(float a, float b) {
    u32 ua = __float_as_uint(a) + 0x8000u;
    u32 ub = __float_as_uint(b) + 0x8000u;
    return __builtin_amdgcn_perm(ub, ua, 0x07060302);
}

// ---------------------------------------------------------------------------
// Kernel 1: prep = wcvt (blocks 0..255) + gn_stats (blocks 256..511).
// wcvt: wq/wk/wv/wo fp32 -> bf16; wq pre-scaled by log2(e)/16 (exp2 path).
// gn_stats: part[bg*4+quarter] = {sum, sumsq} over 8192 elems.
// ---------------------------------------------------------------------------
__global__ __launch_bounds__(256) void prep_kernel(
    const float* __restrict__ wq, const float* __restrict__ wk,
    const float* __restrict__ wv, const float* __restrict__ wo,
    const float* __restrict__ x, u16* __restrict__ Wbf,
    float2* __restrict__ part) {
    int blk = blockIdx.x;
    int t = threadIdx.x;
    if (blk < 256) {
        int base = (blk * 256 + t) * 4;
        int p = base >> 16;
        int off = base & 65535;
        const float* W = (p == 0) ? wq : ((p == 1) ? wk : ((p == 2) ? wv : wo));
        float sc = (p == 0) ? 0.09014009048f : 1.0f;   // log2(e)/16
        float4 v = *(const float4*)(W + off);
        uint2 pk;
        pk.x = pkbf(v.x * sc, v.y * sc);
        pk.y = pkbf(v.z * sc, v.w * sc);
        *(uint2*)(Wbf + base) = pk;
        return;
    }
    int sblk = blk - 256;
    int bg = sblk >> 2, quarter = sblk & 3;
    const float* xp = x + (size_t)bg * 32768 + quarter * 8192;

    float s = 0.f, ss = 0.f;
#pragma unroll
    for (int rep = 0; rep < 8; ++rep) {
        float4 v = *(const float4*)(xp + t * 4 + rep * 1024);
        s += v.x + v.y + v.z + v.w;
        ss += v.x * v.x + v.y * v.y + v.z * v.z + v.w * v.w;
    }
    for (int off = 1; off < 64; off <<= 1) {
        s += __shfl_xor(s, off);
        ss += __shfl_xor(ss, off);
    }
    __shared__ float red[8];
    int lane = t & 63, w = t >> 6;
    if (lane == 0) { red[w] = s; red[4 + w] = ss; }
    __syncthreads();
    if (t == 0) {
        part[sblk] = make_float2(red[0] + red[1] + red[2] + red[3],
                                 red[4] + red[5] + red[6] + red[7]);
    }
}

// ---------------------------------------------------------------------------
// Kernel 2: QKV GEMM with FUSED GroupNorm B-stage (no normT round-trip).
// ---------------------------------------------------------------------------
__global__ __launch_bounds__(256) void qkv_gemm(
    const float* __restrict__ x, const float* __restrict__ gw,
    const float* __restrict__ gb, const float2* __restrict__ part,
    const u16* __restrict__ Wbf,
    u16* __restrict__ Q, u16* __restrict__ K, u16* __restrict__ V) {
    int b = blockIdx.y & 1;
    int p = blockIdx.y >> 1;
    const u16* W = Wbf + p * 65536;
    int m0 = (blockIdx.x & 1) * 128;
    int n0 = (blockIdx.x >> 1) * 64;

    __shared__ u16 a_s[128 * 40];
    __shared__ u16 b_s[64 * 40];
    __shared__ float wgt_s[256], bia_s[256];

    int t = threadIdx.x;
    int lane = t & 63, wave = t >> 6;
    int wm = wave & 1, wn = wave >> 1;
    int r = lane & 15, qd = lane >> 4;

    {
        int c = t;
        int g = c >> 3;
        float s = 0.f, ss = 0.f;
#pragma unroll
        for (int q = 0; q < 4; ++q) {
            float2 pp = part[(b * 32 + g) * 4 + q];
            s += pp.x; ss += pp.y;
        }
        float mu = s * (1.f / 32768.f);
        float var = ss * (1.f / 32768.f) - mu * mu;
        float rstd = rsqrtf(var + 1e-5f);
        float wg = gw[c] * rstd;
        wgt_s[c] = wg;
        bia_s[c] = gb[c] - mu * wg;
    }
    __syncthreads();

    f32x4 acc[4][2];
#pragma unroll
    for (int i = 0; i < 4; ++i)
#pragma unroll
        for (int j = 0; j < 2; ++j) acc[i][j] = (f32x4){0.f, 0.f, 0.f, 0.f};

    int srow = t >> 1;
    int scp = (t & 1) * 16;
    int cb = t & 31;
    int s4 = (t >> 5) * 4;

    for (int kk = 0; kk < 256; kk += 32) {
        __syncthreads();
        {
            const u16* src = W + (m0 + srow) * 256 + kk + scp;
            *(uint4*)(a_s + srow * 40 + scp) = *(const uint4*)(src);
            *(uint4*)(a_s + srow * 40 + scp + 8) = *(const uint4*)(src + 8);
        }
        {
            int c = kk + cb;
            float wg = wgt_s[c], bi = bia_s[c];
            const float* xsrc = x + (size_t)(b * 256 + c) * 4096 + n0;
            float4 v0 = *(const float4*)(xsrc + s4);
            float4 v1 = *(const float4*)(xsrc + s4 + 32);
            u16* d0 = b_s + s4 * 40 + cb;
            d0[0]   = f2bf(v0.x * wg + bi);
            d0[40]  = f2bf(v0.y * wg + bi);
            d0[80]  = f2bf(v0.z * wg + bi);
            d0[120] = f2bf(v0.w * wg + bi);
            u16* d1 = b_s + (s4 + 32) * 40 + cb;
            d1[0]   = f2bf(v1.x * wg + bi);
            d1[40]  = f2bf(v1.y * wg + bi);
            d1[80]  = f2bf(v1.z * wg + bi);
            d1[120] = f2bf(v1.w * wg + bi);
        }
        __syncthreads();

        bf16x8 af[4], bf[2];
#pragma unroll
        for (int mt = 0; mt < 4; ++mt)
            af[mt] = *(const bf16x8*)(a_s + (wm * 64 + mt * 16 + r) * 40 + qd * 8);
#pragma unroll
        for (int nt = 0; nt < 2; ++nt)
            bf[nt] = *(const bf16x8*)(b_s + (wn * 32 + nt * 16 + r) * 40 + qd * 8);
        if (p == 2) {
#pragma unroll
            for (int mt = 0; mt < 4; ++mt)
#pragma unroll
                for (int nt = 0; nt < 2; ++nt)
                    acc[mt][nt] = MFMA(bf[nt], af[mt], acc[mt][nt]);
        } else {
#pragma unroll
            for (int mt = 0; mt < 4; ++mt)
#pragma unroll
                for (int nt = 0; nt < 2; ++nt)
                    acc[mt][nt] = MFMA(af[mt], bf[nt], acc[mt][nt]);
        }
    }

    if (p < 2) {
        u16* dst = (p == 0) ? Q : K;
#pragma unroll
        for (int mt = 0; mt < 4; ++mt) {
#pragma unroll
            for (int nt = 0; nt < 2; ++nt) {
                int o0 = m0 + wm * 64 + mt * 16 + qd * 4;
                int s = n0 + wn * 32 + nt * 16 + r;
                int h = o0 >> 6, d0 = o0 & 63;
                uint2 pk;
                pk.x = pkbf(acc[mt][nt][0], acc[mt][nt][1]);
                pk.y = pkbf(acc[mt][nt][2], acc[mt][nt][3]);
                *(uint2*)(dst + ((size_t)((b * 4 + h) * 4096 + s)) * 64 + d0) = pk;
            }
        }
    } else {
#pragma unroll
        for (int mt = 0; mt < 4; ++mt) {
#pragma unroll
            for (int nt = 0; nt < 2; ++nt) {
                int o = m0 + wm * 64 + mt * 16 + r;
                int h = o >> 6, d = o & 63;
                int sb = n0 + wn * 32 + nt * 16 + qd * 4;
                uint2 pk;
                pk.x = pkbf(acc[mt][nt][0], acc[mt][nt][1]);
                pk.y = pkbf(acc[mt][nt][2], acc[mt][nt][3]);
                *(uint2*)(V + ((size_t)((b * 4 + h) * 64 + d)) * 4096 + sb) = pk;
            }
        }
    }
}

// ---------------------------------------------------------------------------
// Kernel 3: flash attention. QT=1: 32 q/wave, ~110 regs -> 4 waves/SIMD;
// grid (8*nsplit, 4096/(32*QT*4)) = 1024 blocks at nsplit=4 -> 4 blocks/CU.
// LDS-free loop, contiguous 16B K/V loads, shfl_xor P C->B exchange,
// exp2-folded scores, barrier-free per-wave epilogue.
// blockIdx.x = bh + 8*sp pins one head's K/V per XCD L2.
// ---------------------------------------------------------------------------
template <int QT>
__global__ __launch_bounds__(256, (QT == 1) ? 4 : 2) void attn_kernel(
    const u16* __restrict__ Q, const u16* __restrict__ K,
    const u16* __restrict__ V, u16* __restrict__ Opart,
    float* __restrict__ Lpart, int nk32) {
    int bh = blockIdx.x & 7, sp = blockIdx.x >> 3;
    int qb = blockIdx.y;
    int t = threadIdx.x, lane = t & 63, w = t >> 6;
    int qn = lane & 31, h = lane >> 5;

    const size_t bhoff = (size_t)bh * 4096 * 64;
    int q0 = (qb * 4 + w) * (32 * QT);
    int kbase = sp * nk32 * 32;

    bf16x8 qf[QT][4];
#pragma unroll
    for (int qt = 0; qt < QT; ++qt)
#pragma unroll
        for (int c = 0; c < 4; ++c)
            qf[qt][c] = *(const bf16x8*)(Q + bhoff +
                (size_t)(q0 + qt * 32 + qn) * 64 + c * 16 + h * 8);

    f32x16 oacc[2][QT];
#pragma unroll
    for (int dt = 0; dt < 2; ++dt)
#pragma unroll
        for (int qt = 0; qt < QT; ++qt)
#pragma unroll
            for (int i = 0; i < 16; ++i) oacc[dt][qt][i] = 0.f;
    float lacc[QT];
#pragma unroll
    for (int qt = 0; qt < QT; ++qt) lacc[qt] = 0.f;

    const u16* Kp = K + bhoff;
    const u16* Vp = V + bhoff;

    for (int kt = 0; kt < nk32; ++kt) {
        int k0 = kbase + kt * 32;
        bf16x8 kf[4];
#pragma unroll
        for (int c = 0; c < 4; ++c)
            kf[c] = *(const bf16x8*)(Kp + (size_t)(k0 + qn) * 64 + c * 16 + h * 8);
        bf16x8 vf[2][2];
#pragma unroll
        for (int dt = 0; dt < 2; ++dt)
#pragma unroll
            for (int kc = 0; kc < 2; ++kc)
                vf[dt][kc] = *(const bf16x8*)(Vp +
                    (size_t)(dt * 32 + qn) * 4096 + k0 + kc * 16 + h * 8);

#pragma unroll
        for (int qt = 0; qt < QT; ++qt) {
            f32x16 s;
#pragma unroll
            for (int i = 0; i < 16; ++i) s[i] = 0.f;
#pragma unroll
            for (int c = 0; c < 4; ++c) s = MFMA32(kf[c], qf[qt][c], s);

            float e[16];
            float ls = 0.f;
#pragma unroll
            for (int i = 0; i < 16; ++i) {
                e[i] = __builtin_amdgcn_exp2f(s[i]);
                ls += e[i];
            }
            lacc[qt] += ls;

            u32 p[8], rm[8];
#pragma unroll
            for (int i = 0; i < 8; ++i) p[i] = pkbf(e[2 * i], e[2 * i + 1]);
#pragma unroll
            for (int i = 0; i < 8; ++i)
                rm[i] = (u32)__shfl_xor((int)p[i], 32);

            u32 a0 = h ? rm[2] : p[0], a1 = h ? rm[3] : p[1];
            u32 a2 = h ? p[2] : rm[0], a3 = h ? p[3] : rm[1];
            u32 b0 = h ? rm[6] : p[4], b1 = h ? rm[7] : p[5];
            u32 b2 = h ? p[6] : rm[4], b3 = h ? p[7] : rm[5];
            uint4 pau = {a0, a1, a2, a3};
            uint4 pbu = {b0, b1, b2, b3};
            bf16x8 pA = *(const bf16x8*)&pau;
            bf16x8 pB = *(const bf16x8*)&pbu;

#pragma unroll
            for (int dt = 0; dt < 2; ++dt) {
                oacc[dt][qt] = MFMA32(vf[dt][0], pA, oacc[dt][qt]);
                oacc[dt][qt] = MFMA32(vf[dt][1], pB, oacc[dt][qt]);
            }
        }
    }

    float lfull[QT];
#pragma unroll
    for (int qt = 0; qt < QT; ++qt)
        lfull[qt] = lacc[qt] + __shfl_xor(lacc[qt], 32);

    // epilogue: per-wave 32-row LDS transpose (no barrier; in-wave lgkmcnt)
    __shared__ u16 osw[4][32 * 72];
    u16* my = osw[w];
    size_t obase = ((size_t)sp * 8 + bh) * 4096 + q0;
#pragma unroll
    for (int qt = 0; qt < QT; ++qt) {
#pragma unroll
        for (int dt = 0; dt < 2; ++dt) {
#pragma unroll
            for (int g = 0; g < 4; ++g) {
                int d0 = g * 8 + h * 4 + dt * 32;
                uint2 pk;
                pk.x = pkbf(oacc[dt][qt][4 * g], oacc[dt][qt][4 * g + 1]);
                pk.y = pkbf(oacc[dt][qt][4 * g + 2], oacc[dt][qt][4 * g + 3]);
                *(uint2*)(my + qn * 72 + d0) = pk;
            }
        }
#pragma unroll
        for (int rr = 0; rr < 4; ++rr) {
            int row = rr * 8 + (lane >> 3), ch = lane & 7;
            uint4 v = *(const uint4*)(my + row * 72 + ch * 8);
            *(uint4*)(Opart + (obase + qt * 32 + row) * 64 + ch * 8) = v;
        }
    }
    if (h == 0) {
#pragma unroll
        for (int qt = 0; qt < QT; ++qt)
            Lpart[obase + qt * 32 + qn] = lfull[qt];
    }
}

// ---------------------------------------------------------------------------
// Kernel 4: combine nsplit partials, normalize, write attnT[b][s][c] bf16.
// ---------------------------------------------------------------------------
__global__ __launch_bounds__(256) void attn_combine(
    const u16* __restrict__ Opart, const float* __restrict__ Lpart,
    u16* __restrict__ attnT, int nsplit) {
    int t = threadIdx.x;
    int gr = blockIdx.x * 64 + (t >> 2);      // bh*4096+q
    int d0 = (t & 3) * 16;

    float l = 0.f;
    for (int s = 0; s < nsplit; ++s) l += Lpart[(size_t)s * 32768 + gr];
    float inv = 1.f / l;

    float acc[16];
#pragma unroll
    for (int i = 0; i < 16; ++i) acc[i] = 0.f;
    for (int s = 0; s < nsplit; ++s) {
        const u16* p = Opart + ((size_t)s * 32768 + gr) * 64 + d0;
        uint4 a = *(const uint4*)(p);
        uint4 bq = *(const uint4*)(p + 8);
        const u32* ap = (const u32*)&a;
        const u32* bp = (const u32*)&bq;
#pragma unroll
        for (int j = 0; j < 4; ++j) {
            acc[2 * j]     += __uint_as_float(ap[j] << 16);
            acc[2 * j + 1] += __uint_as_float(ap[j] & 0xFFFF0000u);
            acc[8 + 2 * j]     += __uint_as_float(bp[j] << 16);
            acc[8 + 2 * j + 1] += __uint_as_float(bp[j] & 0xFFFF0000u);
        }
    }
    u32 pk[8];
#pragma unroll
    for (int j = 0; j < 8; ++j)
        pk[j] = pkbf(acc[2 * j] * inv, acc[2 * j + 1] * inv);

    int bh = gr >> 12, q = gr & 4095;
    int b = bh >> 2, hh = bh & 3;
    u16* dst = attnT + ((size_t)(b * 4096 + q)) * 256 + hh * 64 + d0;
    *(uint4*)(dst) = make_uint4(pk[0], pk[1], pk[2], pk[3]);
    *(uint4*)(dst + 8) = make_uint4(pk[4], pk[5], pk[6], pk[7]);
}

// ---------------------------------------------------------------------------
// Kernel 5: output GEMM + bias + residual. 64x64 tiles, grid (256,2)=512.
// ---------------------------------------------------------------------------
__global__ __launch_bounds__(256) void out_gemm(
    const u16* __restrict__ attnT, const u16* __restrict__ W3,
    const float* __restrict__ bo, const float* __restrict__ x,
    float* __restrict__ out) {
    int b = blockIdx.y;
    int m0 = (blockIdx.x & 3) * 64;
    int n0 = (blockIdx.x >> 2) * 64;

    __shared__ u16 a_s[64 * 40];
    __shared__ u16 b_s[64 * 40];

    int t = threadIdx.x;
    int lane = t & 63, wave = t >> 6;
    int wm = wave & 1, wn = wave >> 1;
    int r = lane & 15, qd = lane >> 4;

    const u16* Bsrc = attnT + (size_t)b * 4096 * 256;

    f32x4 acc[2][2];
#pragma unroll
    for (int i = 0; i < 2; ++i)
#pragma unroll
        for (int j = 0; j < 2; ++j) acc[i][j] = (f32x4){0.f, 0.f, 0.f, 0.f};

    int u = t & 127;
    int srow = u >> 1;
    int scp = (u & 1) * 16;

    for (int kk = 0; kk < 256; kk += 32) {
        __syncthreads();
        if (t < 128) {
            const u16* src = W3 + (m0 + srow) * 256 + kk + scp;
            *(uint4*)(a_s + srow * 40 + scp) = *(const uint4*)(src);
            *(uint4*)(a_s + srow * 40 + scp + 8) = *(const uint4*)(src + 8);
        } else {
            const u16* src = Bsrc + (size_t)(n0 + srow) * 256 + kk + scp;
            *(uint4*)(b_s + srow * 40 + scp) = *(const uint4*)(src);
            *(uint4*)(b_s + srow * 40 + scp + 8) = *(const uint4*)(src + 8);
        }
        __syncthreads();

        bf16x8 af[2], bf[2];
#pragma unroll
        for (int mt = 0; mt < 2; ++mt)
            af[mt] = *(const bf16x8*)(a_s + (wm * 32 + mt * 16 + r) * 40 + qd * 8);
#pragma unroll
        for (int nt = 0; nt < 2; ++nt)
            bf[nt] = *(const bf16x8*)(b_s + (wn * 32 + nt * 16 + r) * 40 + qd * 8);
#pragma unroll
        for (int mt = 0; mt < 2; ++mt)
#pragma unroll
            for (int nt = 0; nt < 2; ++nt)
                acc[mt][nt] = MFMA(af[mt], bf[nt], acc[mt][nt]);
    }

#pragma unroll
    for (int mt = 0; mt < 2; ++mt) {
#pragma unroll
        for (int nt = 0; nt < 2; ++nt) {
#pragma unroll
            for (int j = 0; j < 4; ++j) {
                int o = m0 + wm * 32 + mt * 16 + qd * 4 + j;
                int s = n0 + wn * 32 + nt * 16 + r;
                size_t idx = (size_t)(b * 256 + o) * 4096 + s;
                out[idx] = acc[mt][nt][j] + bo[o] + x[idx];
            }
        }
    }
}

// ---------------------------------------------------------------------------
extern "C" void kernel_launch(void* const* d_in, const int* in_sizes, int n_in,
                              void* d_out, int out_size, void* d_ws, size_t ws_size,
                              hipStream_t stream) {
    const float* x = (const float*)d_in[0];
    const float* gn_w = (const float*)d_in[1];
    const float* gn_b = (const float*)d_in[2];
    const float* wq = (const float*)d_in[3];
    const float* wk = (const float*)d_in[4];
    const float* wv = (const float*)d_in[5];
    const float* wo = (const float*)d_in[6];
    const float* bo = (const float*)d_in[7];
    float* out = (float*)d_out;

    char* ws = (char*)d_ws;
    u16* attnT = (u16*)(ws);                        // [0,4M)
    u16* Q     = (u16*)(ws + (4u << 20));           // [b][h][s][d] (scaled log2e/16)
    u16* Kp    = (u16*)(ws + (8u << 20));           // [b][h][s][d]
    u16* Vp    = (u16*)(ws + (12u << 20));          // [b][h][d][s]
    u16* Wbf   = (u16*)(ws + (16u << 20));          // 512 KB
    float2* part = (float2*)(ws + (16u << 20) + 524288);

    size_t opart_off = (size_t)17 << 20;
    size_t ob4 = 4ull * 8 * 4096 * 64 * 2;   // 16.78 MB
    int nsplit = (ws_size >= opart_off + ob4 + 4ull * 32768 * 4 + 4096) ? 4 : 2;
    u16* Opart = (u16*)(ws + opart_off);
    float* Lpart = (float*)(ws + opart_off + (size_t)nsplit * 8 * 4096 * 64 * 2);

    prep_kernel<<<512, 256, 0, stream>>>(wq, wk, wv, wo, x, Wbf, part);
    qkv_gemm<<<dim3(128, 6), 256, 0, stream>>>(x, gn_w, gn_b, part, Wbf, Q, Kp, Vp);
    if (nsplit == 4) {
        // QT=1, 4 waves/SIMD: grid (32, 32) = 1024 blocks = 4 blocks/CU
        attn_kernel<1><<<dim3(32, 32), 256, 0, stream>>>(Q, Kp, Vp, Opart, Lpart, 32);
    } else {
        attn_kernel<1><<<dim3(16, 32), 256, 0, stream>>>(Q, Kp, Vp, Opart, Lpart, 64);
    }
    attn_combine<<<512, 256, 0, stream>>>(Opart, Lpart, attnT, nsplit);
    out_gemm<<<dim3(256, 2), 256, 0, stream>>>(attnT, Wbf + 3 * 65536, bo, x, out);
}

// Round 13
// 166.983 us; speedup vs baseline: 1.3223x; 1.3223x over previous
//
#include <hip/hip_runtime.h>

typedef float f32x4 __attribute__((ext_vector_type(4)));
typedef float f32x16 __attribute__((ext_vector_type(16)));
typedef short bf16x8 __attribute__((ext_vector_type(8)));
typedef unsigned short u16;
typedef unsigned int u32;

#define MFMA(a, b, c) __builtin_amdgcn_mfma_f32_16x16x32_bf16((a), (b), (c), 0, 0, 0)
#define MFMA32(a, b, c) __builtin_amdgcn_mfma_f32_32x32x16_bf16((a), (b), (c), 0, 0, 0)

static __device__ __forceinline__ u16 f2bf(float f) {
    union { float f; u32 u; } v; v.f = f;
    u32 r = v.u + 0x7FFFu + ((v.u >> 16) & 1u);
    return (u16)(r >> 16);
}

// pack two fp32 -> two bf16 in one u32 (a low, b high)
static __device__ __forceinline__ u32 pkbf(float a, float b) {
    u32 ua = __float_as_uint(a) + 0x8000u;
    u32 ub = __float_as_uint(b) + 0x8000u;
    return __builtin_amdgcn_perm(ub, ua, 0x07060302);
}

// ---------------------------------------------------------------------------
// Kernel 1: prep = wcvt (blocks 0..255) + gn_stats (blocks 256..511).
// ---------------------------------------------------------------------------
__global__ __launch_bounds__(256) void prep_kernel(
    const float* __restrict__ wq, const float* __restrict__ wk,
    const float* __restrict__ wv, const float* __restrict__ wo,
    const float* __restrict__ x, u16* __restrict__ Wbf,
    float2* __restrict__ part) {
    int blk = blockIdx.x;
    int t = threadIdx.x;
    if (blk < 256) {
        int base = (blk * 256 + t) * 4;
        int p = base >> 16;
        int off = base & 65535;
        const float* W = (p == 0) ? wq : ((p == 1) ? wk : ((p == 2) ? wv : wo));
        float sc = (p == 0) ? 0.09014009048f : 1.0f;   // log2(e)/16
        float4 v = *(const float4*)(W + off);
        uint2 pk;
        pk.x = pkbf(v.x * sc, v.y * sc);
        pk.y = pkbf(v.z * sc, v.w * sc);
        *(uint2*)(Wbf + base) = pk;
        return;
    }
    int sblk = blk - 256;
    int bg = sblk >> 2, quarter = sblk & 3;
    const float* xp = x + (size_t)bg * 32768 + quarter * 8192;

    float s = 0.f, ss = 0.f;
#pragma unroll
    for (int rep = 0; rep < 8; ++rep) {
        float4 v = *(const float4*)(xp + t * 4 + rep * 1024);
        s += v.x + v.y + v.z + v.w;
        ss += v.x * v.x + v.y * v.y + v.z * v.z + v.w * v.w;
    }
    for (int off = 1; off < 64; off <<= 1) {
        s += __shfl_xor(s, off);
        ss += __shfl_xor(ss, off);
    }
    __shared__ float red[8];
    int lane = t & 63, w = t >> 6;
    if (lane == 0) { red[w] = s; red[4 + w] = ss; }
    __syncthreads();
    if (t == 0) {
        part[sblk] = make_float2(red[0] + red[1] + red[2] + red[3],
                                 red[4] + red[5] + red[6] + red[7]);
    }
}

// ---------------------------------------------------------------------------
// Kernel 2: QKV GEMM with FUSED GroupNorm B-stage (no normT round-trip).
// ---------------------------------------------------------------------------
__global__ __launch_bounds__(256) void qkv_gemm(
    const float* __restrict__ x, const float* __restrict__ gw,
    const float* __restrict__ gb, const float2* __restrict__ part,
    const u16* __restrict__ Wbf,
    u16* __restrict__ Q, u16* __restrict__ K, u16* __restrict__ V) {
    int b = blockIdx.y & 1;
    int p = blockIdx.y >> 1;
    const u16* W = Wbf + p * 65536;
    int m0 = (blockIdx.x & 1) * 128;
    int n0 = (blockIdx.x >> 1) * 64;

    __shared__ u16 a_s[128 * 40];
    __shared__ u16 b_s[64 * 40];
    __shared__ float wgt_s[256], bia_s[256];

    int t = threadIdx.x;
    int lane = t & 63, wave = t >> 6;
    int wm = wave & 1, wn = wave >> 1;
    int r = lane & 15, qd = lane >> 4;

    {
        int c = t;
        int g = c >> 3;
        float s = 0.f, ss = 0.f;
#pragma unroll
        for (int q = 0; q < 4; ++q) {
            float2 pp = part[(b * 32 + g) * 4 + q];
            s += pp.x; ss += pp.y;
        }
        float mu = s * (1.f / 32768.f);
        float var = ss * (1.f / 32768.f) - mu * mu;
        float rstd = rsqrtf(var + 1e-5f);
        float wg = gw[c] * rstd;
        wgt_s[c] = wg;
        bia_s[c] = gb[c] - mu * wg;
    }
    __syncthreads();

    f32x4 acc[4][2];
#pragma unroll
    for (int i = 0; i < 4; ++i)
#pragma unroll
        for (int j = 0; j < 2; ++j) acc[i][j] = (f32x4){0.f, 0.f, 0.f, 0.f};

    int srow = t >> 1;
    int scp = (t & 1) * 16;
    int cb = t & 31;
    int s4 = (t >> 5) * 4;

    for (int kk = 0; kk < 256; kk += 32) {
        __syncthreads();
        {
            const u16* src = W + (m0 + srow) * 256 + kk + scp;
            *(uint4*)(a_s + srow * 40 + scp) = *(const uint4*)(src);
            *(uint4*)(a_s + srow * 40 + scp + 8) = *(const uint4*)(src + 8);
        }
        {
            int c = kk + cb;
            float wg = wgt_s[c], bi = bia_s[c];
            const float* xsrc = x + (size_t)(b * 256 + c) * 4096 + n0;
            float4 v0 = *(const float4*)(xsrc + s4);
            float4 v1 = *(const float4*)(xsrc + s4 + 32);
            u16* d0 = b_s + s4 * 40 + cb;
            d0[0]   = f2bf(v0.x * wg + bi);
            d0[40]  = f2bf(v0.y * wg + bi);
            d0[80]  = f2bf(v0.z * wg + bi);
            d0[120] = f2bf(v0.w * wg + bi);
            u16* d1 = b_s + (s4 + 32) * 40 + cb;
            d1[0]   = f2bf(v1.x * wg + bi);
            d1[40]  = f2bf(v1.y * wg + bi);
            d1[80]  = f2bf(v1.z * wg + bi);
            d1[120] = f2bf(v1.w * wg + bi);
        }
        __syncthreads();

        bf16x8 af[4], bf[2];
#pragma unroll
        for (int mt = 0; mt < 4; ++mt)
            af[mt] = *(const bf16x8*)(a_s + (wm * 64 + mt * 16 + r) * 40 + qd * 8);
#pragma unroll
        for (int nt = 0; nt < 2; ++nt)
            bf[nt] = *(const bf16x8*)(b_s + (wn * 32 + nt * 16 + r) * 40 + qd * 8);
        if (p == 2) {
#pragma unroll
            for (int mt = 0; mt < 4; ++mt)
#pragma unroll
                for (int nt = 0; nt < 2; ++nt)
                    acc[mt][nt] = MFMA(bf[nt], af[mt], acc[mt][nt]);
        } else {
#pragma unroll
            for (int mt = 0; mt < 4; ++mt)
#pragma unroll
                for (int nt = 0; nt < 2; ++nt)
                    acc[mt][nt] = MFMA(af[mt], bf[nt], acc[mt][nt]);
        }
    }

    if (p < 2) {
        u16* dst = (p == 0) ? Q : K;
#pragma unroll
        for (int mt = 0; mt < 4; ++mt) {
#pragma unroll
            for (int nt = 0; nt < 2; ++nt) {
                int o0 = m0 + wm * 64 + mt * 16 + qd * 4;
                int s = n0 + wn * 32 + nt * 16 + r;
                int h = o0 >> 6, d0 = o0 & 63;
                uint2 pk;
                pk.x = pkbf(acc[mt][nt][0], acc[mt][nt][1]);
                pk.y = pkbf(acc[mt][nt][2], acc[mt][nt][3]);
                *(uint2*)(dst + ((size_t)((b * 4 + h) * 4096 + s)) * 64 + d0) = pk;
            }
        }
    } else {
#pragma unroll
        for (int mt = 0; mt < 4; ++mt) {
#pragma unroll
            for (int nt = 0; nt < 2; ++nt) {
                int o = m0 + wm * 64 + mt * 16 + r;
                int h = o >> 6, d = o & 63;
                int sb = n0 + wn * 32 + nt * 16 + qd * 4;
                uint2 pk;
                pk.x = pkbf(acc[mt][nt][0], acc[mt][nt][1]);
                pk.y = pkbf(acc[mt][nt][2], acc[mt][nt][3]);
                *(uint2*)(V + ((size_t)((b * 4 + h) * 64 + d)) * 4096 + sb) = pk;
            }
        }
    }
}

// ---------------------------------------------------------------------------
// Kernel 3: flash attention. QT=2 (R11 structure) + explicit 2-deep register
// double-buffer of K/V frags with CONTIGUOUS 16B loads (untried combo:
// R7's dbuf was confounded by permuted 8B loads). LDS-free loop, shfl_xor
// P C->B exchange, exp2-folded scores, barrier-free per-wave epilogue.
// grid (8*nsplit, 4096/256); blockIdx.x = bh + 8*sp pins K/V per XCD L2.
// ---------------------------------------------------------------------------
struct KVfrag {
    bf16x8 kf[4];
    bf16x8 vf[2][2];
};

static __device__ __forceinline__ void load_kv(
    KVfrag& o, const u16* __restrict__ Kp, const u16* __restrict__ Vp,
    int k0, int qn, int h) {
#pragma unroll
    for (int c = 0; c < 4; ++c)
        o.kf[c] = *(const bf16x8*)(Kp + (size_t)(k0 + qn) * 64 + c * 16 + h * 8);
#pragma unroll
    for (int dt = 0; dt < 2; ++dt)
#pragma unroll
        for (int kc = 0; kc < 2; ++kc)
            o.vf[dt][kc] = *(const bf16x8*)(Vp +
                (size_t)(dt * 32 + qn) * 4096 + k0 + kc * 16 + h * 8);
}

template <int QT>
__global__ __launch_bounds__(256, 2) void attn_kernel(
    const u16* __restrict__ Q, const u16* __restrict__ K,
    const u16* __restrict__ V, u16* __restrict__ Opart,
    float* __restrict__ Lpart, int nk32) {
    int bh = blockIdx.x & 7, sp = blockIdx.x >> 3;
    int qb = blockIdx.y;
    int t = threadIdx.x, lane = t & 63, w = t >> 6;
    int qn = lane & 31, h = lane >> 5;

    const size_t bhoff = (size_t)bh * 4096 * 64;
    int q0 = (qb * 4 + w) * (32 * QT);
    int kbase = sp * nk32 * 32;

    bf16x8 qf[QT][4];
#pragma unroll
    for (int qt = 0; qt < QT; ++qt)
#pragma unroll
        for (int c = 0; c < 4; ++c)
            qf[qt][c] = *(const bf16x8*)(Q + bhoff +
                (size_t)(q0 + qt * 32 + qn) * 64 + c * 16 + h * 8);

    f32x16 oacc[2][QT];
#pragma unroll
    for (int dt = 0; dt < 2; ++dt)
#pragma unroll
        for (int qt = 0; qt < QT; ++qt)
#pragma unroll
            for (int i = 0; i < 16; ++i) oacc[dt][qt][i] = 0.f;
    float lacc[QT];
#pragma unroll
    for (int qt = 0; qt < QT; ++qt) lacc[qt] = 0.f;

    const u16* Kp = K + bhoff;
    const u16* Vp = V + bhoff;

    KVfrag buf0, buf1;
    load_kv(buf0, Kp, Vp, kbase, qn, h);

    auto step = [&](const KVfrag& kv) {
#pragma unroll
        for (int qt = 0; qt < QT; ++qt) {
            f32x16 s;
#pragma unroll
            for (int i = 0; i < 16; ++i) s[i] = 0.f;
#pragma unroll
            for (int c = 0; c < 4; ++c) s = MFMA32(kv.kf[c], qf[qt][c], s);

            float e[16];
            float ls = 0.f;
#pragma unroll
            for (int i = 0; i < 16; ++i) {
                e[i] = __builtin_amdgcn_exp2f(s[i]);
                ls += e[i];
            }
            lacc[qt] += ls;

            u32 p[8], rm[8];
#pragma unroll
            for (int i = 0; i < 8; ++i) p[i] = pkbf(e[2 * i], e[2 * i + 1]);
#pragma unroll
            for (int i = 0; i < 8; ++i)
                rm[i] = (u32)__shfl_xor((int)p[i], 32);

            u32 a0 = h ? rm[2] : p[0], a1 = h ? rm[3] : p[1];
            u32 a2 = h ? p[2] : rm[0], a3 = h ? p[3] : rm[1];
            u32 b0 = h ? rm[6] : p[4], b1 = h ? rm[7] : p[5];
            u32 b2 = h ? p[6] : rm[4], b3 = h ? p[7] : rm[5];
            uint4 pau = {a0, a1, a2, a3};
            uint4 pbu = {b0, b1, b2, b3};
            bf16x8 pA = *(const bf16x8*)&pau;
            bf16x8 pB = *(const bf16x8*)&pbu;

#pragma unroll
            for (int dt = 0; dt < 2; ++dt) {
                oacc[dt][qt] = MFMA32(kv.vf[dt][0], pA, oacc[dt][qt]);
                oacc[dt][qt] = MFMA32(kv.vf[dt][1], pB, oacc[dt][qt]);
            }
        }
    };

    for (int kt = 0; kt < nk32; kt += 2) {
        load_kv(buf1, Kp, Vp, kbase + (kt + 1) * 32, qn, h);
        step(buf0);
        int k2 = (kt + 2 < nk32) ? kbase + (kt + 2) * 32 : kbase;
        load_kv(buf0, Kp, Vp, k2, qn, h);
        step(buf1);
    }

    float lfull[QT];
#pragma unroll
    for (int qt = 0; qt < QT; ++qt)
        lfull[qt] = lacc[qt] + __shfl_xor(lacc[qt], 32);

    // epilogue: per-wave 32-row LDS transpose (no barrier; in-wave lgkmcnt)
    __shared__ u16 osw[4][32 * 72];
    u16* my = osw[w];
    size_t obase = ((size_t)sp * 8 + bh) * 4096 + q0;
#pragma unroll
    for (int qt = 0; qt < QT; ++qt) {
#pragma unroll
        for (int dt = 0; dt < 2; ++dt) {
#pragma unroll
            for (int g = 0; g < 4; ++g) {
                int d0 = g * 8 + h * 4 + dt * 32;
                uint2 pk;
                pk.x = pkbf(oacc[dt][qt][4 * g], oacc[dt][qt][4 * g + 1]);
                pk.y = pkbf(oacc[dt][qt][4 * g + 2], oacc[dt][qt][4 * g + 3]);
                *(uint2*)(my + qn * 72 + d0) = pk;
            }
        }
#pragma unroll
        for (int rr = 0; rr < 4; ++rr) {
            int row = rr * 8 + (lane >> 3), ch = lane & 7;
            uint4 v = *(const uint4*)(my + row * 72 + ch * 8);
            *(uint4*)(Opart + (obase + qt * 32 + row) * 64 + ch * 8) = v;
        }
    }
    if (h == 0) {
#pragma unroll
        for (int qt = 0; qt < QT; ++qt)
            Lpart[obase + qt * 32 + qn] = lfull[qt];
    }
}

// ---------------------------------------------------------------------------
// Kernel 4: combine nsplit partials, normalize, write attnT[b][s][c] bf16.
// ---------------------------------------------------------------------------
__global__ __launch_bounds__(256) void attn_combine(
    const u16* __restrict__ Opart, const float* __restrict__ Lpart,
    u16* __restrict__ attnT, int nsplit) {
    int t = threadIdx.x;
    int gr = blockIdx.x * 64 + (t >> 2);      // bh*4096+q
    int d0 = (t & 3) * 16;

    float l = 0.f;
    for (int s = 0; s < nsplit; ++s) l += Lpart[(size_t)s * 32768 + gr];
    float inv = 1.f / l;

    float acc[16];
#pragma unroll
    for (int i = 0; i < 16; ++i) acc[i] = 0.f;
    for (int s = 0; s < nsplit; ++s) {
        const u16* p = Opart + ((size_t)s * 32768 + gr) * 64 + d0;
        uint4 a = *(const uint4*)(p);
        uint4 bq = *(const uint4*)(p + 8);
        const u32* ap = (const u32*)&a;
        const u32* bp = (const u32*)&bq;
#pragma unroll
        for (int j = 0; j < 4; ++j) {
            acc[2 * j]     += __uint_as_float(ap[j] << 16);
            acc[2 * j + 1] += __uint_as_float(ap[j] & 0xFFFF0000u);
            acc[8 + 2 * j]     += __uint_as_float(bp[j] << 16);
            acc[8 + 2 * j + 1] += __uint_as_float(bp[j] & 0xFFFF0000u);
        }
    }
    u32 pk[8];
#pragma unroll
    for (int j = 0; j < 8; ++j)
        pk[j] = pkbf(acc[2 * j] * inv, acc[2 * j + 1] * inv);

    int bh = gr >> 12, q = gr & 4095;
    int b = bh >> 2, hh = bh & 3;
    u16* dst = attnT + ((size_t)(b * 4096 + q)) * 256 + hh * 64 + d0;
    *(uint4*)(dst) = make_uint4(pk[0], pk[1], pk[2], pk[3]);
    *(uint4*)(dst + 8) = make_uint4(pk[4], pk[5], pk[6], pk[7]);
}

// ---------------------------------------------------------------------------
// Kernel 5: output GEMM + bias + residual. 64x64 tiles, grid (256,2)=512.
// ---------------------------------------------------------------------------
__global__ __launch_bounds__(256) void out_gemm(
    const u16* __restrict__ attnT, const u16* __restrict__ W3,
    const float* __restrict__ bo, const float* __restrict__ x,
    float* __restrict__ out) {
    int b = blockIdx.y;
    int m0 = (blockIdx.x & 3) * 64;
    int n0 = (blockIdx.x >> 2) * 64;

    __shared__ u16 a_s[64 * 40];
    __shared__ u16 b_s[64 * 40];

    int t = threadIdx.x;
    int lane = t & 63, wave = t >> 6;
    int wm = wave & 1, wn = wave >> 1;
    int r = lane & 15, qd = lane >> 4;

    const u16* Bsrc = attnT + (size_t)b * 4096 * 256;

    f32x4 acc[2][2];
#pragma unroll
    for (int i = 0; i < 2; ++i)
#pragma unroll
        for (int j = 0; j < 2; ++j) acc[i][j] = (f32x4){0.f, 0.f, 0.f, 0.f};

    int u = t & 127;
    int srow = u >> 1;
    int scp = (u & 1) * 16;

    for (int kk = 0; kk < 256; kk += 32) {
        __syncthreads();
        if (t < 128) {
            const u16* src = W3 + (m0 + srow) * 256 + kk + scp;
            *(uint4*)(a_s + srow * 40 + scp) = *(const uint4*)(src);
            *(uint4*)(a_s + srow * 40 + scp + 8) = *(const uint4*)(src + 8);
        } else {
            const u16* src = Bsrc + (size_t)(n0 + srow) * 256 + kk + scp;
            *(uint4*)(b_s + srow * 40 + scp) = *(const uint4*)(src);
            *(uint4*)(b_s + srow * 40 + scp + 8) = *(const uint4*)(src + 8);
        }
        __syncthreads();

        bf16x8 af[2], bf[2];
#pragma unroll
        for (int mt = 0; mt < 2; ++mt)
            af[mt] = *(const bf16x8*)(a_s + (wm * 32 + mt * 16 + r) * 40 + qd * 8);
#pragma unroll
        for (int nt = 0; nt < 2; ++nt)
            bf[nt] = *(const bf16x8*)(b_s + (wn * 32 + nt * 16 + r) * 40 + qd * 8);
#pragma unroll
        for (int mt = 0; mt < 2; ++mt)
#pragma unroll
            for (int nt = 0; nt < 2; ++nt)
                acc[mt][nt] = MFMA(af[mt], bf[nt], acc[mt][nt]);
    }

#pragma unroll
    for (int mt = 0; mt < 2; ++mt) {
#pragma unroll
        for (int nt = 0; nt < 2; ++nt) {
#pragma unroll
            for (int j = 0; j < 4; ++j) {
                int o = m0 + wm * 32 + mt * 16 + qd * 4 + j;
                int s = n0 + wn * 32 + nt * 16 + r;
                size_t idx = (size_t)(b * 256 + o) * 4096 + s;
                out[idx] = acc[mt][nt][j] + bo[o] + x[idx];
            }
        }
    }
}

// ---------------------------------------------------------------------------
extern "C" void kernel_launch(void* const* d_in, const int* in_sizes, int n_in,
                              void* d_out, int out_size, void* d_ws, size_t ws_size,
                              hipStream_t stream) {
    const float* x = (const float*)d_in[0];
    const float* gn_w = (const float*)d_in[1];
    const float* gn_b = (const float*)d_in[2];
    const float* wq = (const float*)d_in[3];
    const float* wk = (const float*)d_in[4];
    const float* wv = (const float*)d_in[5];
    const float* wo = (const float*)d_in[6];
    const float* bo = (const float*)d_in[7];
    float* out = (float*)d_out;

    char* ws = (char*)d_ws;
    u16* attnT = (u16*)(ws);                        // [0,4M)
    u16* Q     = (u16*)(ws + (4u << 20));           // [b][h][s][d] (scaled log2e/16)
    u16* Kp    = (u16*)(ws + (8u << 20));           // [b][h][s][d]
    u16* Vp    = (u16*)(ws + (12u << 20));          // [b][h][d][s]
    u16* Wbf   = (u16*)(ws + (16u << 20));          // 512 KB
    float2* part = (float2*)(ws + (16u << 20) + 524288);

    size_t opart_off = (size_t)17 << 20;
    size_t ob4 = 4ull * 8 * 4096 * 64 * 2;   // 16.78 MB
    int nsplit = (ws_size >= opart_off + ob4 + 4ull * 32768 * 4 + 4096) ? 4 : 2;
    u16* Opart = (u16*)(ws + opart_off);
    float* Lpart = (float*)(ws + opart_off + (size_t)nsplit * 8 * 4096 * 64 * 2);

    prep_kernel<<<512, 256, 0, stream>>>(wq, wk, wv, wo, x, Wbf, part);
    qkv_gemm<<<dim3(128, 6), 256, 0, stream>>>(x, gn_w, gn_b, part, Wbf, Q, Kp, Vp);
    if (nsplit == 4) {
        attn_kernel<2><<<dim3(32, 16), 256, 0, stream>>>(Q, Kp, Vp, Opart, Lpart, 32);
    } else {
        attn_kernel<2><<<dim3(16, 16), 256, 0, stream>>>(Q, Kp, Vp, Opart, Lpart, 64);
    }
    attn_combine<<<512, 256, 0, stream>>>(Opart, Lpart, attnT, nsplit);
    out_gemm<<<dim3(256, 2), 256, 0, stream>>>(attnT, Wbf + 3 * 65536, bo, x, out);
}